// Round 6
// baseline (871.256 us; speedup 1.0000x reference)
//
#include <hip/hip_runtime.h>
#include <hip/hip_bf16.h>

#define E_EDGES 1000000

typedef __attribute__((ext_vector_type(8))) short bf16x8;
typedef __attribute__((ext_vector_type(4))) float f32x4;

#define WAITV(N) asm volatile("s_waitcnt vmcnt(" #N ")" ::: "memory")

__device__ __forceinline__ short f2bf(float f) {
    union { __hip_bfloat16 b; short s; } u;
    u.b = __float2bfloat16(f);
    return u.s;
}
__device__ __forceinline__ bf16x8 pack8(float4 a, float4 b) {
    bf16x8 r;
    r[0]=f2bf(a.x); r[1]=f2bf(a.y); r[2]=f2bf(a.z); r[3]=f2bf(a.w);
    r[4]=f2bf(b.x); r[5]=f2bf(b.y); r[6]=f2bf(b.z); r[7]=f2bf(b.w);
    return r;
}
__device__ __forceinline__ float4 ld4(const float* p) {
    return *reinterpret_cast<const float4*>(p);
}
__device__ __forceinline__ float silu1(float x) { return x / (1.f + __expf(-x)); }
__device__ __forceinline__ float tanh1(float x) {
    float e = __expf(2.f * x);
    return 1.f - 2.f / (e + 1.f);
}

// ---------------- weight pre-pack: f32 -> bf16 frags in CHUNK-LINEAR order ------
// 196 frags of 512 shorts; frag f element (l*8+j) = W[k(l,j)][n(l)].
//   frags 0..95   : W_in,  chunk cs=seg*4+ks (12 chunks), within: nt=0..7
//   frags 96..159 : W_time, chunk ch (8): ch<4 -> scale cols j=8+2ch+jj; else shift j=2(ch-4)+jj; within: jj*4+ks
//   frags 160..191: W1, chunk ch (4): nt=2ch+(sub>>2), ks=sub&3
//   frags 192..195: W2 padded, ks=0..3
__global__ void pack_weights_kernel(const float* __restrict__ Wt,
                                    const float* __restrict__ Win,
                                    const float* __restrict__ W1,
                                    const float* __restrict__ W2,
                                    short* __restrict__ ws)
{
    int gid = blockIdx.x * 256 + threadIdx.x;
    if (gid >= 196 * 512) return;
    int frag = gid >> 9, within = gid & 511;
    int l = within >> 3, j = within & 7;
    int lg = l >> 4, ln = l & 15;
    int krow = (lg << 3) + j;              // k offset within a 32-wide k-step
    float v;
    if (frag < 96) {
        int cs = frag >> 3, nt = frag & 7;
        int seg = cs >> 2, ks = cs & 3;
        int k = seg * 128 + ks * 32 + krow;
        v = Win[k * 128 + nt * 16 + ln];
    } else if (frag < 160) {
        int t = frag - 96, ch = t >> 3, sub = t & 7;
        int jj = sub >> 2, ks = sub & 3;
        int jcol = (ch < 4) ? (8 + 2 * ch + jj) : (2 * (ch - 4) + jj);
        int k = ks * 32 + krow;
        v = Wt[k * 256 + jcol * 16 + ln];
    } else if (frag < 192) {
        int t = frag - 160, ch = t >> 3, sub = t & 7;
        int nt = 2 * ch + (sub >> 2), ks = sub & 3;
        int k = ks * 32 + krow;
        v = W1[k * 128 + nt * 16 + ln];
    } else {
        int ks = frag - 192;
        int k = ks * 32 + krow;
        v = (ln < 4) ? W2[k * 4 + ln] : 0.0f;
    }
    ws[gid] = f2bf(v);
}

// ---- async staging: one global_load_lds per fragment (64 lanes x 16 B), 0 VGPRs ----
__device__ __forceinline__ void stage_frag(const short* gsrc, short* ldst) {
    __builtin_amdgcn_global_load_lds(
        (const __attribute__((address_space(1))) void*)gsrc,
        (__attribute__((address_space(3))) void*)ldst, 16, 0, 0);
}

// +b_in then LayerNorm over 128 cols; row lives in a 16-lane quarter-group.
__device__ __forceinline__ void ln_inplace(f32x4 (&aX)[8], const float* __restrict__ bin, int ln) {
    #pragma unroll
    for (int nt = 0; nt < 8; ++nt) {
        float bv = bin[(nt<<4) + ln];
        #pragma unroll
        for (int r = 0; r < 4; ++r) aX[nt][r] += bv;
    }
    #pragma unroll
    for (int r = 0; r < 4; ++r) {
        float p = 0.f, q = 0.f;
        #pragma unroll
        for (int nt = 0; nt < 8; ++nt) { float x = aX[nt][r]; p += x; q += x*x; }
        #pragma unroll
        for (int d2 = 1; d2 < 16; d2 <<= 1) { p += __shfl_xor(p, d2); q += __shfl_xor(q, d2); }
        float mean = p * 0.0078125f;
        float var  = q * 0.0078125f - mean * mean;
        float rstd = rsqrtf(var + 1e-6f);
        #pragma unroll
        for (int nt = 0; nt < 8; ++nt)
            aX[nt][r] = (aX[nt][r] - mean) * rstd;
    }
}

// ------ fused edge kernel: 4 waves x 32 edges; waves SHARE staged weight chunks ------
__global__ __launch_bounds__(256, 3)
void edge_kernel(const float* __restrict__ h,
                 const float* __restrict__ pos,
                 const float* __restrict__ ea,
                 const float* __restrict__ dst_f,
                 const float* __restrict__ temb,
                 const float* __restrict__ adj,
                 const float* __restrict__ btime,
                 const float* __restrict__ bin,
                 const float* __restrict__ b1,
                 const float* __restrict__ cscale,
                 const int*   __restrict__ ei,
                 const short* __restrict__ ws,
                 float* __restrict__ out)
{
    __shared__ __align__(16) short Wb[2][4096];      // 2 x 8 KB weight chunk dbuf (shared by 4 waves)
    __shared__ __align__(16) short Tb[4][16 * 136];  // per-wave transpose buffer (seq per tile)
    __shared__ int   sIr[4][32];
    __shared__ float sCd[4][3][32];
    __shared__ float sAdj[4][3][32];

    const int tid = threadIdx.x;
    const int w   = tid >> 6;
    const int l   = tid & 63;
    const int ln  = l & 15;
    const int lg  = l >> 4;
    const int kb  = lg << 3;
    const int e0w = blockIdx.x * 128 + w * 32;
    const int em0 = e0w + ln;
    const int em1 = e0w + 16 + ln;
    const int em0c = min(em0, E_EDGES - 1);
    const int em1c = min(em1, E_EDGES - 1);

    const int ir0 = ei[em0c];
    const int ir1 = ei[em1c];
    const int ic0 = ei[E_EDGES + em0c];
    const int ic1 = ei[E_EDGES + em1c];

    // wave w stages frags {2w, 2w+1} of an 8-frag chunk (2 loads/wave/chunk)
    #define STAGE8(p) { \
        const short* g_ = ws + (p) * 4096 + (w*2) * 512 + l * 8; \
        short* d_ = &Wb[(p) & 1][(w*2) * 512]; \
        stage_frag(g_, d_); \
        stage_frag(g_ + 512, d_ + 512); }
    // W2 chunk (4 frags): wave w stages frag w (1 load)
    #define STAGEW2() { \
        stage_frag(ws + 24 * 4096 + w * 512 + l * 8, &Wb[0][w * 512]); }

    // ---- prologue: seg0 A-operands + first weight chunk + geometry ----
    float4 Ab[2][2][8];     // [parity][tile][slot]
    #pragma unroll
    for (int ks = 0; ks < 4; ++ks) {
        Ab[0][0][2*ks]   = ld4(h + (long)ir0 * 128 + ks*32 + kb);
        Ab[0][0][2*ks+1] = ld4(h + (long)ir0 * 128 + ks*32 + kb + 4);
        Ab[0][1][2*ks]   = ld4(h + (long)ir1 * 128 + ks*32 + kb);
        Ab[0][1][2*ks+1] = ld4(h + (long)ir1 * 128 + ks*32 + kb + 4);
    }
    STAGE8(0);

    if (l < 32) {
        int e  = e0w + l;
        int ec = min(e, E_EDGES - 1);
        int ir = ei[ec];
        int ic = ei[E_EDGES + ec];
        sIr[w][l] = ir;
        float dx = pos[ir*3+0] - pos[ic*3+0];
        float dy = pos[ir*3+1] - pos[ic*3+1];
        float dz = pos[ir*3+2] - pos[ic*3+2];
        float nrm = sqrtf(dx*dx + dy*dy + dz*dz);
        float s = cscale[0] / fmaxf(nrm, 1e-8f);
        sCd[w][0][l] = dx * s;
        sCd[w][1][l] = dy * s;
        sCd[w][2][l] = dz * s;
        sAdj[w][0][l] = adj[ec*3+0];
        sAdj[w][1][l] = adj[ec*3+1];
        sAdj[w][2][l] = adj[ec*3+2];
    }

    f32x4 accX0[8], accX1[8];
    #pragma unroll
    for (int i = 0; i < 8; ++i) {
        accX0[i] = (f32x4){0.f,0.f,0.f,0.f};
        accX1[i] = (f32x4){0.f,0.f,0.f,0.f};
    }
    float4 At0[8], At1[8];

    // ---- X = h_input @ W_in : 12 shared chunks ----
    #pragma unroll
    for (int c = 0; c < 12; ++c) {
        if (c < 11) { STAGE8(c + 1); } else { STAGE8(12); }
        if (c == 1) {            // seg1 A (h[col]) -> parity 1
            #pragma unroll
            for (int ks = 0; ks < 4; ++ks) {
                Ab[1][0][2*ks]   = ld4(h + (long)ic0 * 128 + ks*32 + kb);
                Ab[1][0][2*ks+1] = ld4(h + (long)ic0 * 128 + ks*32 + kb + 4);
                Ab[1][1][2*ks]   = ld4(h + (long)ic1 * 128 + ks*32 + kb);
                Ab[1][1][2*ks+1] = ld4(h + (long)ic1 * 128 + ks*32 + kb + 4);
            }
        }
        if (c == 5) {            // seg2 A (ea|dist) -> parity 0
            #pragma unroll
            for (int ks = 0; ks < 4; ++ks) {
                const float* q0 = (ks < 2) ? (ea + (long)em0c*64 + ks*32 + kb)
                                           : (dst_f + (long)em0c*64 + (ks-2)*32 + kb);
                const float* q1 = (ks < 2) ? (ea + (long)em1c*64 + ks*32 + kb)
                                           : (dst_f + (long)em1c*64 + (ks-2)*32 + kb);
                Ab[0][0][2*ks]   = ld4(q0);
                Ab[0][0][2*ks+1] = ld4(q0 + 4);
                Ab[0][1][2*ks]   = ld4(q1);
                Ab[0][1][2*ks+1] = ld4(q1 + 4);
            }
        }
        if (c == 9) {            // temb rows for the T stage
            #pragma unroll
            for (int ks = 0; ks < 4; ++ks) {
                At0[2*ks]   = ld4(temb + (long)em0c * 128 + ks*32 + kb);
                At0[2*ks+1] = ld4(temb + (long)em0c * 128 + ks*32 + kb + 4);
                At1[2*ks]   = ld4(temb + (long)em1c * 128 + ks*32 + kb);
                At1[2*ks+1] = ld4(temb + (long)em1c * 128 + ks*32 + kb + 4);
            }
        }
        // ledger: stage=2/chunk; A-batches(16) at c in {1,5,9}
        if (c == 1 || c == 2 || c == 5 || c == 6 || c == 9 || c == 10) { WAITV(18); }
        else { WAITV(2); }
        __builtin_amdgcn_s_barrier();            // chunk c visible to all waves
        {
            const int ks = c & 3, par = (c >> 2) & 1;
            bf16x8 af0 = pack8(Ab[par][0][2*ks], Ab[par][0][2*ks+1]);
            bf16x8 af1 = pack8(Ab[par][1][2*ks], Ab[par][1][2*ks+1]);
            const short* wb = &Wb[c & 1][0];
            #pragma unroll
            for (int nt = 0; nt < 8; ++nt) {
                bf16x8 b = *reinterpret_cast<const bf16x8*>(&wb[nt*512 + l*8]);
                accX0[nt] = __builtin_amdgcn_mfma_f32_16x16x32_bf16(af0, b, accX0[nt], 0, 0, 0);
                accX1[nt] = __builtin_amdgcn_mfma_f32_16x16x32_bf16(af1, b, accX1[nt], 0, 0, 0);
            }
        }
        __builtin_amdgcn_s_barrier();            // buffer free for re-stage
    }

    // ---- bias + LayerNorm ----
    ln_inplace(accX0, bin, ln);
    ln_inplace(accX1, bin, ln);

    // ---- silu(temb) fragments ----
    bf16x8 ttf0[4], ttf1[4];
    #pragma unroll
    for (int ks = 0; ks < 4; ++ks) {
        float4 a0 = At0[2*ks], b0 = At0[2*ks+1];
        float4 a1 = At1[2*ks], b1v = At1[2*ks+1];
        a0.x=silu1(a0.x); a0.y=silu1(a0.y); a0.z=silu1(a0.z); a0.w=silu1(a0.w);
        b0.x=silu1(b0.x); b0.y=silu1(b0.y); b0.z=silu1(b0.z); b0.w=silu1(b0.w);
        a1.x=silu1(a1.x); a1.y=silu1(a1.y); a1.z=silu1(a1.z); a1.w=silu1(a1.w);
        b1v.x=silu1(b1v.x); b1v.y=silu1(b1v.y); b1v.z=silu1(b1v.z); b1v.w=silu1(b1v.w);
        ttf0[ks] = pack8(a0, b0);
        ttf1[ks] = pack8(a1, b1v);
    }

    // ---- T stage: 8 shared chunks, FiLM inline ----
    #pragma unroll
    for (int t = 0; t < 8; ++t) {
        if (t < 7) { STAGE8(13 + t); } else { STAGE8(20); }
        WAITV(2);
        __builtin_amdgcn_s_barrier();
        {
            const short* wb = &Wb[t & 1][0];     // (12+t)&1
            #pragma unroll
            for (int jj = 0; jj < 2; ++jj) {
                f32x4 t0 = (f32x4){0.f,0.f,0.f,0.f};
                f32x4 t1 = (f32x4){0.f,0.f,0.f,0.f};
                #pragma unroll
                for (int ks = 0; ks < 4; ++ks) {
                    bf16x8 b = *reinterpret_cast<const bf16x8*>(&wb[(jj*4+ks)*512 + l*8]);
                    t0 = __builtin_amdgcn_mfma_f32_16x16x32_bf16(ttf0[ks], b, t0, 0, 0, 0);
                    t1 = __builtin_amdgcn_mfma_f32_16x16x32_bf16(ttf1[ks], b, t1, 0, 0, 0);
                }
                if (t < 4) {
                    const int jx = 2*t + jj;
                    float bsc = btime[128 + (jx<<4) + ln];
                    #pragma unroll
                    for (int r = 0; r < 4; ++r) {
                        accX0[jx][r] *= (1.f + t0[r] + bsc);
                        accX1[jx][r] *= (1.f + t1[r] + bsc);
                    }
                } else {
                    const int jx = 2*(t-4) + jj;
                    float bsh = btime[(jx<<4) + ln];
                    #pragma unroll
                    for (int r = 0; r < 4; ++r) {
                        accX0[jx][r] += t0[r] + bsh;
                        accX1[jx][r] += t1[r] + bsh;
                    }
                }
            }
        }
        __builtin_amdgcn_s_barrier();
    }

    // ---- transpose inv (C-layout -> A-layout), wave-local, sequential per tile ----
    short* tbW = &Tb[w][0];
    bf16x8 iaf0[4], iaf1[4];
    #pragma unroll
    for (int nt = 0; nt < 8; ++nt)
        #pragma unroll
        for (int r = 0; r < 4; ++r)
            tbW[((lg<<2) + r)*136 + (nt<<4) + ln] = f2bf(accX0[nt][r]);
    #pragma unroll
    for (int ks = 0; ks < 4; ++ks)
        iaf0[ks] = *reinterpret_cast<const bf16x8*>(&tbW[ln*136 + (ks<<5) + kb]);
    #pragma unroll
    for (int nt = 0; nt < 8; ++nt)
        #pragma unroll
        for (int r = 0; r < 4; ++r)
            tbW[((lg<<2) + r)*136 + (nt<<4) + ln] = f2bf(accX1[nt][r]);
    #pragma unroll
    for (int ks = 0; ks < 4; ++ks)
        iaf1[ks] = *reinterpret_cast<const bf16x8*>(&tbW[ln*136 + (ks<<5) + kb]);

    // ---- W1 stage: 4 shared chunks ----
    f32x4 accY0[8], accY1[8];
    #pragma unroll
    for (int i = 0; i < 8; ++i) {
        accY0[i] = (f32x4){0.f,0.f,0.f,0.f};
        accY1[i] = (f32x4){0.f,0.f,0.f,0.f};
    }
    #pragma unroll
    for (int u = 0; u < 4; ++u) {
        if (u < 3) { STAGE8(21 + u); WAITV(2); }
        else       { STAGEW2();      WAITV(1); }
        __builtin_amdgcn_s_barrier();
        {
            const short* wb = &Wb[u & 1][0];     // (20+u)&1
            #pragma unroll
            for (int s = 0; s < 2; ++s) {
                const int nt = 2*u + s;
                #pragma unroll
                for (int ks = 0; ks < 4; ++ks) {
                    bf16x8 b = *reinterpret_cast<const bf16x8*>(&wb[(s*4+ks)*512 + l*8]);
                    accY0[nt] = __builtin_amdgcn_mfma_f32_16x16x32_bf16(iaf0[ks], b, accY0[nt], 0, 0, 0);
                    accY1[nt] = __builtin_amdgcn_mfma_f32_16x16x32_bf16(iaf1[ks], b, accY1[nt], 0, 0, 0);
                }
            }
        }
        __builtin_amdgcn_s_barrier();
    }

    // ---- silu + transpose back, sequential per tile ----
    bf16x8 yaf0[4], yaf1[4];
    #pragma unroll
    for (int nt = 0; nt < 8; ++nt) {
        float bv = b1[(nt<<4) + ln];
        #pragma unroll
        for (int r = 0; r < 4; ++r)
            tbW[((lg<<2) + r)*136 + (nt<<4) + ln] = f2bf(silu1(accY0[nt][r] + bv));
    }
    #pragma unroll
    for (int ks = 0; ks < 4; ++ks)
        yaf0[ks] = *reinterpret_cast<const bf16x8*>(&tbW[ln*136 + (ks<<5) + kb]);
    #pragma unroll
    for (int nt = 0; nt < 8; ++nt) {
        float bv = b1[(nt<<4) + ln];
        #pragma unroll
        for (int r = 0; r < 4; ++r)
            tbW[((lg<<2) + r)*136 + (nt<<4) + ln] = f2bf(silu1(accY1[nt][r] + bv));
    }
    #pragma unroll
    for (int ks = 0; ks < 4; ++ks)
        yaf1[ks] = *reinterpret_cast<const bf16x8*>(&tbW[ln*136 + (ks<<5) + kb]);

    // ---- W2 stage (chunk 24 in Wb[0]) ----
    WAITV(0);
    __builtin_amdgcn_s_barrier();
    f32x4 accZ0 = (f32x4){0.f,0.f,0.f,0.f};
    f32x4 accZ1 = (f32x4){0.f,0.f,0.f,0.f};
    {
        const short* wb = &Wb[0][0];
        #pragma unroll
        for (int ks = 0; ks < 4; ++ks) {
            bf16x8 b = *reinterpret_cast<const bf16x8*>(&wb[ks*512 + l*8]);
            accZ0 = __builtin_amdgcn_mfma_f32_16x16x32_bf16(yaf0[ks], b, accZ0, 0, 0, 0);
            accZ1 = __builtin_amdgcn_mfma_f32_16x16x32_bf16(yaf1[ks], b, accZ1, 0, 0, 0);
        }
    }

    // ---- tanh, head-mean, predicated atomic scatter ----
    #pragma unroll
    for (int r = 0; r < 4; ++r) {
        {
            int   m = (lg<<2) + r;
            float z = tanh1(accZ0[r]);
            float wt = (ln == 0) ? 1.0f : ((ln < 4) ? sAdj[w][ln-1][m] : 0.0f);
            float v = z * wt;
            v += __shfl_xor(v, 1);
            v += __shfl_xor(v, 2);
            v += __shfl_xor(v, 4);
            v += __shfl_xor(v, 8);
            float s = v * 0.25f;
            if (ln < 3 && (e0w + m) < E_EDGES)
                atomicAdd(&out[(long)sIr[w][m]*3 + ln], sCd[w][ln][m] * s);
        }
        {
            int   m = 16 + (lg<<2) + r;
            float z = tanh1(accZ1[r]);
            float wt = (ln == 0) ? 1.0f : ((ln < 4) ? sAdj[w][ln-1][m] : 0.0f);
            float v = z * wt;
            v += __shfl_xor(v, 1);
            v += __shfl_xor(v, 2);
            v += __shfl_xor(v, 4);
            v += __shfl_xor(v, 8);
            float s = v * 0.25f;
            if (ln < 3 && (e0w + m) < E_EDGES)
                atomicAdd(&out[(long)sIr[w][m]*3 + ln], sCd[w][ln][m] * s);
        }
    }
    #undef STAGE8
    #undef STAGEW2
}

extern "C" void kernel_launch(void* const* d_in, const int* in_sizes, int n_in,
                              void* d_out, int out_size, void* d_ws, size_t ws_size,
                              hipStream_t stream) {
    const float* h     = (const float*)d_in[0];
    const float* pos   = (const float*)d_in[1];
    const float* ea    = (const float*)d_in[2];
    const float* dist  = (const float*)d_in[3];
    const float* temb  = (const float*)d_in[4];
    const float* adj   = (const float*)d_in[5];
    const float* Wt    = (const float*)d_in[6];
    const float* bt    = (const float*)d_in[7];
    const float* Win   = (const float*)d_in[8];
    const float* bin   = (const float*)d_in[9];
    const float* W1    = (const float*)d_in[10];
    const float* b1    = (const float*)d_in[11];
    const float* W2    = (const float*)d_in[12];
    const float* cs    = (const float*)d_in[13];
    const int*   ei    = (const int*)d_in[14];
    float*       out   = (float*)d_out;
    short*       ws    = (short*)d_ws;

    pack_weights_kernel<<<(196*512 + 255) / 256, 256, 0, stream>>>(Wt, Win, W1, W2, ws);
    hipMemcpyAsync(out, pos, (size_t)out_size * sizeof(float),
                   hipMemcpyDeviceToDevice, stream);
    edge_kernel<<<(E_EDGES + 127) / 128, 256, 0, stream>>>(h, pos, ea, dist, temb, adj,
                                                           bt, bin, b1, cs, ei, ws, out);
}

// Round 7
// 640.732 us; speedup vs baseline: 1.3598x; 1.3598x over previous
//
#include <hip/hip_runtime.h>
#include <hip/hip_bf16.h>

#define E_EDGES 1000000

typedef __attribute__((ext_vector_type(8))) short bf16x8;
typedef __attribute__((ext_vector_type(4))) float f32x4;

#define WAITV(N) asm volatile("s_waitcnt vmcnt(" #N ")" ::: "memory")
#define BAR()    __builtin_amdgcn_s_barrier()

__device__ __forceinline__ short f2bf(float f) {
    union { __hip_bfloat16 b; short s; } u;
    u.b = __float2bfloat16(f);
    return u.s;
}
__device__ __forceinline__ bf16x8 pack8(float4 a, float4 b) {
    bf16x8 r;
    r[0]=f2bf(a.x); r[1]=f2bf(a.y); r[2]=f2bf(a.z); r[3]=f2bf(a.w);
    r[4]=f2bf(b.x); r[5]=f2bf(b.y); r[6]=f2bf(b.z); r[7]=f2bf(b.w);
    return r;
}
__device__ __forceinline__ float4 ld4(const float* p) {
    return *reinterpret_cast<const float4*>(p);
}
__device__ __forceinline__ float silu1(float x) { return x / (1.f + __expf(-x)); }
__device__ __forceinline__ float tanh1(float x) {
    float e = __expf(2.f * x);
    return 1.f - 2.f / (e + 1.f);
}

// ---------------- weight pre-pack: f32 -> bf16 frags in CHUNK-LINEAR order ------
// 196 frags of 512 shorts; frag f element (l*8+j) = W[k(l,j)][n(l)].
//   frags 0..95   : W_in,  chunk cs=seg*4+ks (12 chunks), within: nt=0..7
//   frags 96..159 : W_time, chunk ch (8): ch<4 -> scale cols j=8+2ch+jj; else shift j=2(ch-4)+jj; within: jj*4+ks
//   frags 160..191: W1, chunk ch (4): nt=2ch+(sub>>2), ks=sub&3
//   frags 192..195: W2 padded, ks=0..3
__global__ void pack_weights_kernel(const float* __restrict__ Wt,
                                    const float* __restrict__ Win,
                                    const float* __restrict__ W1,
                                    const float* __restrict__ W2,
                                    short* __restrict__ ws)
{
    int gid = blockIdx.x * 256 + threadIdx.x;
    if (gid >= 196 * 512) return;
    int frag = gid >> 9, within = gid & 511;
    int l = within >> 3, j = within & 7;
    int lg = l >> 4, ln = l & 15;
    int krow = (lg << 3) + j;
    float v;
    if (frag < 96) {
        int cs = frag >> 3, nt = frag & 7;
        int seg = cs >> 2, ks = cs & 3;
        int k = seg * 128 + ks * 32 + krow;
        v = Win[k * 128 + nt * 16 + ln];
    } else if (frag < 160) {
        int t = frag - 96, ch = t >> 3, sub = t & 7;
        int jj = sub >> 2, ks = sub & 3;
        int jcol = (ch < 4) ? (8 + 2 * ch + jj) : (2 * (ch - 4) + jj);
        int k = ks * 32 + krow;
        v = Wt[k * 256 + jcol * 16 + ln];
    } else if (frag < 192) {
        int t = frag - 160, ch = t >> 3, sub = t & 7;
        int nt = 2 * ch + (sub >> 2), ks = sub & 3;
        int k = ks * 32 + krow;
        v = W1[k * 128 + nt * 16 + ln];
    } else {
        int ks = frag - 192;
        int k = ks * 32 + krow;
        v = (ln < 4) ? W2[k * 4 + ln] : 0.0f;
    }
    ws[gid] = f2bf(v);
}

__device__ __forceinline__ void stage_frag(const short* gsrc, short* ldst) {
    __builtin_amdgcn_global_load_lds(
        (const __attribute__((address_space(1))) void*)gsrc,
        (__attribute__((address_space(3))) void*)ldst, 16, 0, 0);
}

// ------ fused edge kernel: 4 waves x 16 edges; waves share staged weight chunks ------
__global__ __launch_bounds__(256, 3)
void edge_kernel(const float* __restrict__ h,
                 const float* __restrict__ pos,
                 const float* __restrict__ ea,
                 const float* __restrict__ dst_f,
                 const float* __restrict__ temb,
                 const float* __restrict__ adj,
                 const float* __restrict__ btime,
                 const float* __restrict__ bin,
                 const float* __restrict__ b1,
                 const float* __restrict__ cscale,
                 const int*   __restrict__ ei,
                 const short* __restrict__ ws,
                 float* __restrict__ out)
{
    __shared__ __align__(16) short Wb[2][4096];      // 2 x 8 KB shared weight chunk dbuf
    __shared__ __align__(16) short Tb[4][16 * 136];  // per-wave transpose buffer

    const int tid = threadIdx.x;
    const int w   = tid >> 6;
    const int l   = tid & 63;
    const int ln  = l & 15;
    const int lg  = l >> 4;
    const int kb  = lg << 3;
    const int e0w = blockIdx.x * 64 + w * 16;
    const int em  = e0w + ln;                // this lane's edge (1 tile/wave)

    const int ir = ei[em];
    const int ic = ei[E_EDGES + em];

    // geometry raw loads NOW, math deferred to epilogue (no LDS, no divergence)
    const float px0 = pos[ir*3+0], py0 = pos[ir*3+1], pz0 = pos[ir*3+2];
    const float px1 = pos[ic*3+0], py1 = pos[ic*3+1], pz1 = pos[ic*3+2];
    const float a0  = adj[em*3+0], a1  = adj[em*3+1], a2  = adj[em*3+2];
    const float csc = cscale[0];

    // wave w stages frags {2w, 2w+1} of each 8-frag chunk
    #define STAGE8(p) { \
        const short* g_ = ws + (p) * 4096 + (w*2) * 512 + l * 8; \
        short* d_ = &Wb[(p) & 1][(w*2) * 512]; \
        stage_frag(g_, d_); \
        stage_frag(g_ + 512, d_ + 512); }
    #define STAGEW2() { \
        stage_frag(ws + 24 * 4096 + w * 512 + l * 8, &Wb[0][w * 512]); }

    // ---- prologue: seg0 A loads, then first weight chunk ----
    float4 Abuf[8];
    #pragma unroll
    for (int k2 = 0; k2 < 4; ++k2) {
        Abuf[2*k2]   = ld4(h + (long)ir * 128 + k2*32 + kb);
        Abuf[2*k2+1] = ld4(h + (long)ir * 128 + k2*32 + kb + 4);
    }
    STAGE8(0);

    f32x4 accX[8];
    #pragma unroll
    for (int i = 0; i < 8; ++i) accX[i] = (f32x4){0.f,0.f,0.f,0.f};
    bf16x8 af[4];

    // ---- X = h_input @ W_in : 12 shared chunks ----
    #pragma unroll
    for (int c = 0; c < 12; ++c) {
        if (c < 11) { STAGE8(c + 1); } else { STAGE8(12); }
        if (c == 1) {            // seg1: h[col]
            #pragma unroll
            for (int k2 = 0; k2 < 4; ++k2) {
                Abuf[2*k2]   = ld4(h + (long)ic * 128 + k2*32 + kb);
                Abuf[2*k2+1] = ld4(h + (long)ic * 128 + k2*32 + kb + 4);
            }
        }
        if (c == 5) {            // seg2: ea | dist
            #pragma unroll
            for (int k2 = 0; k2 < 4; ++k2) {
                const float* q = (k2 < 2) ? (ea    + (long)em*64 + k2*32 + kb)
                                          : (dst_f + (long)em*64 + (k2-2)*32 + kb);
                Abuf[2*k2]   = ld4(q);
                Abuf[2*k2+1] = ld4(q + 4);
            }
        }
        if (c == 9) {            // temb rows for T stage
            #pragma unroll
            for (int k2 = 0; k2 < 4; ++k2) {
                Abuf[2*k2]   = ld4(temb + (long)em * 128 + k2*32 + kb);
                Abuf[2*k2+1] = ld4(temb + (long)em * 128 + k2*32 + kb + 4);
            }
        }
        // ledger: 2 stage ops/chunk; 8-load A batches issued at c in {1,5,9}
        if (c == 1 || c == 2 || c == 5 || c == 6 || c == 9 || c == 10) { WAITV(10); }
        else { WAITV(2); }
        BAR();                                   // chunk c visible to all waves
        if (c == 0 || c == 4 || c == 8) {        // pack this seg's A fragments
            #pragma unroll
            for (int k2 = 0; k2 < 4; ++k2) af[k2] = pack8(Abuf[2*k2], Abuf[2*k2+1]);
        }
        {
            const int ks = c & 3;
            const short* wb = &Wb[c & 1][0];
            #pragma unroll
            for (int nt = 0; nt < 8; ++nt) {
                bf16x8 b = *reinterpret_cast<const bf16x8*>(&wb[nt*512 + l*8]);
                accX[nt] = __builtin_amdgcn_mfma_f32_16x16x32_bf16(af[ks], b, accX[nt], 0, 0, 0);
            }
        }
        BAR();                                   // buffer free for re-stage
    }

    // ---- bias + LayerNorm (row lives in a 16-lane quarter-group) ----
    #pragma unroll
    for (int nt = 0; nt < 8; ++nt) {
        float bv = bin[(nt<<4) + ln];
        #pragma unroll
        for (int r = 0; r < 4; ++r) accX[nt][r] += bv;
    }
    #pragma unroll
    for (int r = 0; r < 4; ++r) {
        float p = 0.f, q = 0.f;
        #pragma unroll
        for (int nt = 0; nt < 8; ++nt) { float x = accX[nt][r]; p += x; q += x*x; }
        #pragma unroll
        for (int d2 = 1; d2 < 16; d2 <<= 1) { p += __shfl_xor(p, d2); q += __shfl_xor(q, d2); }
        float mean = p * 0.0078125f;
        float var  = q * 0.0078125f - mean * mean;
        float rstd = rsqrtf(var + 1e-6f);
        #pragma unroll
        for (int nt = 0; nt < 8; ++nt)
            accX[nt][r] = (accX[nt][r] - mean) * rstd;
    }

    // ---- silu(temb) fragments from Abuf ----
    bf16x8 ttf[4];
    #pragma unroll
    for (int k2 = 0; k2 < 4; ++k2) {
        float4 va = Abuf[2*k2], vb = Abuf[2*k2+1];
        va.x=silu1(va.x); va.y=silu1(va.y); va.z=silu1(va.z); va.w=silu1(va.w);
        vb.x=silu1(vb.x); vb.y=silu1(vb.y); vb.z=silu1(vb.z); vb.w=silu1(vb.w);
        ttf[k2] = pack8(va, vb);
    }

    // ---- T stage: 8 shared chunks, FiLM inline ----
    #pragma unroll
    for (int t = 0; t < 8; ++t) {
        if (t < 7) { STAGE8(13 + t); } else { STAGE8(20); }
        WAITV(2);
        BAR();
        {
            const short* wb = &Wb[t & 1][0];     // (12+t)&1 == t&1
            #pragma unroll
            for (int jj = 0; jj < 2; ++jj) {
                f32x4 tt = (f32x4){0.f,0.f,0.f,0.f};
                #pragma unroll
                for (int ks = 0; ks < 4; ++ks) {
                    bf16x8 b = *reinterpret_cast<const bf16x8*>(&wb[(jj*4+ks)*512 + l*8]);
                    tt = __builtin_amdgcn_mfma_f32_16x16x32_bf16(ttf[ks], b, tt, 0, 0, 0);
                }
                if (t < 4) {
                    const int jx = 2*t + jj;
                    float bsc = btime[128 + (jx<<4) + ln];
                    #pragma unroll
                    for (int r = 0; r < 4; ++r) accX[jx][r] *= (1.f + tt[r] + bsc);
                } else {
                    const int jx = 2*(t-4) + jj;
                    float bsh = btime[(jx<<4) + ln];
                    #pragma unroll
                    for (int r = 0; r < 4; ++r) accX[jx][r] += tt[r] + bsh;
                }
            }
        }
        BAR();
    }

    // ---- transpose inv (C-layout -> A-layout) through per-wave LDS ----
    short* tbW = &Tb[w][0];
    #pragma unroll
    for (int nt = 0; nt < 8; ++nt)
        #pragma unroll
        for (int r = 0; r < 4; ++r)
            tbW[((lg<<2) + r)*136 + (nt<<4) + ln] = f2bf(accX[nt][r]);
    bf16x8 iaf[4];
    #pragma unroll
    for (int ks = 0; ks < 4; ++ks)
        iaf[ks] = *reinterpret_cast<const bf16x8*>(&tbW[ln*136 + (ks<<5) + kb]);

    // ---- W1 stage: 4 shared chunks ----
    f32x4 accY[8];
    #pragma unroll
    for (int i = 0; i < 8; ++i) accY[i] = (f32x4){0.f,0.f,0.f,0.f};
    #pragma unroll
    for (int u = 0; u < 4; ++u) {
        if (u < 3) { STAGE8(21 + u); WAITV(2); }
        else       { STAGEW2();      WAITV(1); }
        BAR();
        {
            const short* wb = &Wb[u & 1][0];     // (20+u)&1 == u&1
            #pragma unroll
            for (int s = 0; s < 2; ++s) {
                const int nt = 2*u + s;
                #pragma unroll
                for (int ks = 0; ks < 4; ++ks) {
                    bf16x8 b = *reinterpret_cast<const bf16x8*>(&wb[(s*4+ks)*512 + l*8]);
                    accY[nt] = __builtin_amdgcn_mfma_f32_16x16x32_bf16(iaf[ks], b, accY[nt], 0, 0, 0);
                }
            }
        }
        BAR();
    }

    // ---- silu + transpose back ----
    #pragma unroll
    for (int nt = 0; nt < 8; ++nt) {
        float bv = b1[(nt<<4) + ln];
        #pragma unroll
        for (int r = 0; r < 4; ++r)
            tbW[((lg<<2) + r)*136 + (nt<<4) + ln] = f2bf(silu1(accY[nt][r] + bv));
    }
    bf16x8 yaf[4];
    #pragma unroll
    for (int ks = 0; ks < 4; ++ks)
        yaf[ks] = *reinterpret_cast<const bf16x8*>(&tbW[ln*136 + (ks<<5) + kb]);

    // ---- W2 stage (chunk 24, Wb[0]) ----
    WAITV(0);
    BAR();
    f32x4 accZ = (f32x4){0.f,0.f,0.f,0.f};
    {
        const short* wb = &Wb[0][0];
        #pragma unroll
        for (int ks = 0; ks < 4; ++ks) {
            bf16x8 b = *reinterpret_cast<const bf16x8*>(&wb[ks*512 + l*8]);
            accZ = __builtin_amdgcn_mfma_f32_16x16x32_bf16(yaf[ks], b, accZ, 0, 0, 0);
        }
    }

    // ---- epilogue: geometry math + tanh + head-mean + atomic scatter ----
    {
        float dx = px0 - px1, dy = py0 - py1, dz = pz0 - pz1;
        float nrm = sqrtf(dx*dx + dy*dy + dz*dz);
        float sc  = csc / fmaxf(nrm, 1e-8f);
        float cdx = dx * sc, cdy = dy * sc, cdz = dz * sc;
        #pragma unroll
        for (int r = 0; r < 4; ++r) {
            const int m = (lg<<2) + r;           // edge within the wave tile
            float z  = tanh1(accZ[r]);
            float w0 = __shfl(a0, m), w1 = __shfl(a1, m), w2 = __shfl(a2, m);
            int   irm  = __shfl(ir, m);
            float cdxm = __shfl(cdx, m), cdym = __shfl(cdy, m), cdzm = __shfl(cdz, m);
            float wt = (ln == 0) ? 1.0f : (ln == 1 ? w0 : (ln == 2 ? w1 : (ln == 3 ? w2 : 0.0f)));
            float v = z * wt;
            v += __shfl_xor(v, 1);
            v += __shfl_xor(v, 2);               // heads 0..3 summed within 4-lane group
            float s = v * 0.25f;
            if (ln < 3) {
                float cdc = (ln == 0) ? cdxm : (ln == 1 ? cdym : cdzm);
                atomicAdd(&out[(long)irm*3 + ln], cdc * s);
            }
        }
    }
    #undef STAGE8
    #undef STAGEW2
}

extern "C" void kernel_launch(void* const* d_in, const int* in_sizes, int n_in,
                              void* d_out, int out_size, void* d_ws, size_t ws_size,
                              hipStream_t stream) {
    const float* h     = (const float*)d_in[0];
    const float* pos   = (const float*)d_in[1];
    const float* ea    = (const float*)d_in[2];
    const float* dist  = (const float*)d_in[3];
    const float* temb  = (const float*)d_in[4];
    const float* adj   = (const float*)d_in[5];
    const float* Wt    = (const float*)d_in[6];
    const float* bt    = (const float*)d_in[7];
    const float* Win   = (const float*)d_in[8];
    const float* bin   = (const float*)d_in[9];
    const float* W1    = (const float*)d_in[10];
    const float* b1    = (const float*)d_in[11];
    const float* W2    = (const float*)d_in[12];
    const float* cs    = (const float*)d_in[13];
    const int*   ei    = (const int*)d_in[14];
    float*       out   = (float*)d_out;
    short*       ws    = (short*)d_ws;

    pack_weights_kernel<<<(196*512 + 255) / 256, 256, 0, stream>>>(Wt, Win, W1, W2, ws);
    hipMemcpyAsync(out, pos, (size_t)out_size * sizeof(float),
                   hipMemcpyDeviceToDevice, stream);
    edge_kernel<<<E_EDGES / 64, 256, 0, stream>>>(h, pos, ea, dist, temb, adj,
                                                  bt, bin, b1, cs, ei, ws, out);
}